// Round 9
// baseline (81.701 us; speedup 1.0000x reference)
//
#include <hip/hip_runtime.h>
#include <hip/hip_bf16.h>

#define S_ 8192
#define H_ 8
#define D_ 64
#define M_ 64
#define BH_ 32
#define CPK_ 80          // buf1/partial row stride (c 0..79, den at c=64)
#define NCHK 32          // phase-K chunks (1024 blocks of 2 waves)
#define NCHQ 16
#define TILE 64
#define QTILES (S_ / NCHQ / TILE)   // 8

typedef short bf16x8 __attribute__((ext_vector_type(8)));
typedef float f32x4 __attribute__((ext_vector_type(4)));

constexpr float XS_ = 0.35355339059327373f * 1.4426950408889634f; // D^-1/4 * log2(e)
constexpr float HS_ = 0.34657359027997264f;                        // ln2/2
constexpr float EPS_ = 1e-6f;

__device__ __forceinline__ unsigned short f2bf(float f) {
    unsigned int u = __float_as_uint(f);
    u += 0x7FFFu + ((u >> 16) & 1u);          // RNE
    return (unsigned short)(u >> 16);
}
__device__ __forceinline__ unsigned int pkbf(float lo, float hi) {
    __hip_bfloat162 t = __float22bfloat162_rn(float2{lo, hi});
    return *reinterpret_cast<unsigned int*>(&t);
}
__device__ __forceinline__ float fexp2(float x) { return __builtin_amdgcn_exp2f(x); }

#define MFMA(a, b, c) __builtin_amdgcn_mfma_f32_16x16x32_bf16((a), (b), (c), 0, 0, 0)
#define SWZ(byteoff, row) ((byteoff) ^ (((row) & 7) << 4))

#define GLDS(src, dst) __builtin_amdgcn_global_load_lds( \
    (const __attribute__((address_space(1))) void*)(src), \
    (__attribute__((address_space(3))) void*)(dst), 16, 0, 0)

// ---------------------------------------------------------------------------
// Phase K — global_load_lds staging (zero VGPR in the load path; the DMA
// queue, not registers, holds in-flight data, so the compiler cannot
// serialize loads via register recycling — the r3..r8 59.5us invariant).
// 2 waves/block, wave-independent; 4 LDS buffers/wave (k 4KB + v 4KB);
// SELF-ADDRESSED DMA: lane sources exactly the 16B it reads back at
// lane*16 (conflict-free ds_read_b128, no swizzle). Counted vmcnt waits
// (24/16/8/0) keep >=2 tile-pairs in flight; sched_barrier after each wait.
// Math (P-MFMA, sigma-register E, EV) identical to r8 (verified).
// ---------------------------------------------------------------------------
__global__ void __launch_bounds__(128)
fa_k(const float* __restrict__ ks, const float* __restrict__ vs,
     const float* __restrict__ proj, float* __restrict__ partial)
{
    __shared__ __align__(16) char pool[2][4][8192];   // [wave][buf][k|v] 64KB

    const int chunk = blockIdx.x;
    const int bh    = blockIdx.y;
    const int b = bh >> 3, h = bh & 7;
    const int tid = threadIdx.x, wid = tid >> 6, lane = tid & 63;
    const int l15 = lane & 15, g = lane >> 4;

    const size_t rs = (size_t)H_ * D_;
    const float* kb = ks + ((size_t)b * S_ * H_ + h) * D_;
    const float* vb = vs + ((size_t)b * S_ * H_ + h) * D_;
    const int rbase = chunk * 256 + wid * 128;        // 8 tiles of 16 rows

    // proj B-fragments (issued first => compiler waits them w/o draining DMAs)
    bf16x8 pf[4][2];
#pragma unroll
    for (int mt = 0; mt < 4; ++mt)
#pragma unroll
        for (int kk = 0; kk < 2; ++kk) {
            const float* p = proj + (mt * 16 + l15) * D_ + kk * 32 + g * 8;
            float4 a = *(const float4*)p, c = *(const float4*)(p + 4);
            union { bf16x8 v; unsigned int u[4]; } F;
            F.u[0] = pkbf(a.x, a.y); F.u[1] = pkbf(a.z, a.w);
            F.u[2] = pkbf(c.x, c.y); F.u[3] = pkbf(c.z, c.w);
            pf[mt][kk] = F.v;
        }

    bf16x8 onef = {0, 0, 0, 0, 0, 0, 0, 0};
    if (l15 == 0) {
#pragma unroll
        for (int j = 0; j < 8; ++j) onef[j] = (short)0x3F80;
    }

    f32x4 acc[4][5];
#pragma unroll
    for (int mt = 0; mt < 4; ++mt)
#pragma unroll
        for (int ci = 0; ci < 5; ++ci) acc[mt][ci] = (f32x4){0.f, 0.f, 0.f, 0.f};

    // stage tile t into buf t&3: 8 DMA ops (4 k + 4 v), 1KB each.
    // instr i covers f32 cols c0(i) = (i>>1)*32 + (i&1)*4 + 8*g of row l15;
    // HW writes LDS at base + lane*16 (self-addressed: read back at lane*16).
    auto stage = [&](int t) {
        char* kd = pool[wid][t & 3];
        char* vd = kd + 4096;
        const float* krow = kb + (size_t)(rbase + t * 16 + l15) * rs;
        const float* vrow = vb + (size_t)(rbase + t * 16 + l15) * rs;
#pragma unroll
        for (int i = 0; i < 4; ++i) {
            int c0 = (i >> 1) * 32 + (i & 1) * 4 + 8 * g;
            GLDS(krow + c0, kd + i * 1024);
            GLDS(vrow + c0, vd + i * 1024);
        }
    };

    f32x4 paE[4], paO[4];
    float hrE[4], hrO[4];

    auto consumeP = [&](int t, f32x4* pa, float* hr) {
        const char* kd = pool[wid][t & 3];
        f32x4 r0 = *(const f32x4*)(kd + lane * 16);
        f32x4 r1 = *(const f32x4*)(kd + 1024 + lane * 16);
        f32x4 r2 = *(const f32x4*)(kd + 2048 + lane * 16);
        f32x4 r3 = *(const f32x4*)(kd + 3072 + lane * 16);
        float kx[16];
#pragma unroll
        for (int j = 0; j < 4; ++j) {
            kx[j]      = r0[j] * XS_;
            kx[4 + j]  = r1[j] * XS_;
            kx[8 + j]  = r2[j] * XS_;
            kx[12 + j] = r3[j] * XS_;
        }
        float sq = 0.f;
#pragma unroll
        for (int j = 0; j < 16; ++j) sq += kx[j] * kx[j];
        sq += __shfl_xor(sq, 16);
        sq += __shfl_xor(sq, 32);
        float hrow = sq * HS_ + 3.0f;

        union { bf16x8 v; unsigned int u[4]; } A0, A1;
#pragma unroll
        for (int i = 0; i < 4; ++i) {
            A0.u[i] = pkbf(kx[2 * i], kx[2 * i + 1]);
            A1.u[i] = pkbf(kx[8 + 2 * i], kx[9 + 2 * i]);
        }
#pragma unroll
        for (int mt = 0; mt < 4; ++mt) {
            pa[mt] = (f32x4){0.f, 0.f, 0.f, 0.f};
            pa[mt] = MFMA(A0.v, pf[mt][0], pa[mt]);
            pa[mt] = MFMA(A1.v, pf[mt][1], pa[mt]);
        }
#pragma unroll
        for (int r = 0; r < 4; ++r) hr[r] = __shfl(hrow, 4 * g + r);
    };

    // EV over tiles t (even, paE) and t+1 (odd, paO): sigma A-layout
    // (j 0..3 = even rows 4g+r, j 4..7 = odd rows 4g+r) as r8 (verified).
    auto EV = [&](int t) {
        const char* vE = pool[wid][t & 3] + 4096;
        const char* vO = pool[wid][(t + 1) & 3] + 4096;
        bf16x8 eA[4];
#pragma unroll
        for (int mt = 0; mt < 4; ++mt) {
            union { bf16x8 v; unsigned int u[4]; } E;
            E.u[0] = pkbf(fexp2(paE[mt][0] - hrE[0]), fexp2(paE[mt][1] - hrE[1]));
            E.u[1] = pkbf(fexp2(paE[mt][2] - hrE[2]), fexp2(paE[mt][3] - hrE[3]));
            E.u[2] = pkbf(fexp2(paO[mt][0] - hrO[0]), fexp2(paO[mt][1] - hrO[1]));
            E.u[3] = pkbf(fexp2(paO[mt][2] - hrO[2]), fexp2(paO[mt][3] - hrO[3]));
            eA[mt] = E.v;
        }
#pragma unroll
        for (int ct = 0; ct < 4; ++ct) {
            int c = ct * 16 + l15;
            int ic = ((c >> 5) << 1) | ((c >> 2) & 1);
            int boff = ic * 1024 + ((c & 31) >> 3) * 256 + (c & 3) * 4 + 64 * g;
            float e0 = *(const float*)(vE + boff);
            float e1 = *(const float*)(vE + boff + 16);
            float e2 = *(const float*)(vE + boff + 32);
            float e3 = *(const float*)(vE + boff + 48);
            float o0 = *(const float*)(vO + boff);
            float o1 = *(const float*)(vO + boff + 16);
            float o2 = *(const float*)(vO + boff + 32);
            float o3 = *(const float*)(vO + boff + 48);
            union { bf16x8 v; unsigned int u[4]; } B;
            B.u[0] = pkbf(e0, e1); B.u[1] = pkbf(e2, e3);
            B.u[2] = pkbf(o0, o1); B.u[3] = pkbf(o2, o3);
#pragma unroll
            for (int mt = 0; mt < 4; ++mt)
                acc[mt][ct] = MFMA(eA[mt], B.v, acc[mt][ct]);
        }
#pragma unroll
        for (int mt = 0; mt < 4; ++mt)
            acc[mt][4] = MFMA(eA[mt], onef, acc[mt][4]);
    };

    stage(0); stage(1); stage(2); stage(3);   // 32 DMA ops in flight

#define PAIR(T, W1, W2, DOSTAGE)                                   \
    asm volatile("s_waitcnt vmcnt(" #W1 ")" ::: "memory");         \
    __builtin_amdgcn_sched_barrier(0);                             \
    consumeP(T, paE, hrE);                                         \
    asm volatile("s_waitcnt vmcnt(" #W2 ")" ::: "memory");         \
    __builtin_amdgcn_sched_barrier(0);                             \
    consumeP(T + 1, paO, hrO);                                     \
    EV(T);                                                         \
    if (DOSTAGE) { stage(T + 4); stage(T + 5); }

    PAIR(0, 24, 16, 1)
    PAIR(2, 24, 16, 1)
    PAIR(4, 24, 16, 0)
    PAIR(6, 8, 0, 0)
#undef PAIR

    // 2-wave reduce (red aliases pool; all DMAs drained by vmcnt(0) above)
    __syncthreads();
    float* red = (float*)pool;
    for (int i = tid; i < M_ * CPK_; i += 128) red[i] = 0.f;
    __syncthreads();
    for (int w = 0; w < 2; ++w) {
        if (wid == w) {
#pragma unroll
            for (int mt = 0; mt < 4; ++mt)
#pragma unroll
                for (int ct = 0; ct < 5; ++ct)
#pragma unroll
                    for (int r = 0; r < 4; ++r)
                        red[(mt * 16 + 4 * g + r) * CPK_ + ct * 16 + l15] +=
                            acc[mt][ct][r];
        }
        __syncthreads();
    }
    float* dst = partial + ((size_t)bh * NCHK + chunk) * (M_ * CPK_);
    for (int i = tid; i < M_ * CPK_; i += 128) dst[i] = red[i];
}

// ---------------------------------------------------------------------------
// Reduce partials over chunks -> buf1[bh][m][CPK_]
// ---------------------------------------------------------------------------
__global__ void __launch_bounds__(256)
fa_r(const float* __restrict__ partial, float* __restrict__ buf1, int nch)
{
    int e = blockIdx.x * 256 + threadIdx.x;
    if (e >= BH_ * M_ * CPK_) return;
    int bh = e / (M_ * CPK_);
    int r  = e - bh * (M_ * CPK_);
    const float* src = partial + (size_t)bh * nch * (M_ * CPK_) + r;
    float s0 = 0.f, s1 = 0.f, s2 = 0.f, s3 = 0.f;
    int ch = 0;
    for (; ch + 4 <= nch; ch += 4) {
        s0 += src[(size_t)(ch + 0) * (M_ * CPK_)];
        s1 += src[(size_t)(ch + 1) * (M_ * CPK_)];
        s2 += src[(size_t)(ch + 2) * (M_ * CPK_)];
        s3 += src[(size_t)(ch + 3) * (M_ * CPK_)];
    }
    for (; ch < nch; ++ch) s0 += src[(size_t)ch * (M_ * CPK_)];
    buf1[e] = (s0 + s1) + (s2 + s3);
}

// ---------------------------------------------------------------------------
// Phase Q: unchanged (r8). P = mfma(Qscaled, projT); e = exp2(P - h);
// D[c][qrow] = mfma(buf1T, E_T); den = row c=64; out = num/den.
// ---------------------------------------------------------------------------
__global__ void __launch_bounds__(256)
fa_q(const float* __restrict__ qs, const float* __restrict__ proj,
     const float* __restrict__ buf1, float* __restrict__ out)
{
    const int chunk = blockIdx.x;
    const int bh    = blockIdx.y;
    const int b = bh >> 3, h = bh & 7;
    const int tid = threadIdx.x, wid = tid >> 6, lane = tid & 63;
    const int l15 = lane & 15, g = lane >> 4;

    __shared__ __align__(16) char eLb[2][TILE * M_ * 2];
    __shared__ __align__(16) char b1tb[CPK_ * M_ * 2];

    const int rows = S_ / NCHQ;
    const int s0 = chunk * rows;
    const size_t rs = (size_t)H_ * D_;
    const float* qb = qs + ((size_t)b * S_ * H_ + h) * D_;

    const float* b1 = buf1 + (size_t)bh * (M_ * CPK_);
    for (int i = tid; i < M_ * CPK_; i += 256) {
        int m = i / CPK_, c = i - m * CPK_;
        *(unsigned short*)(b1tb + SWZ(c * 128 + 2 * m, c)) = f2bf(b1[i]);
    }

    bf16x8 pf[4][2];
#pragma unroll
    for (int mt = 0; mt < 4; ++mt)
#pragma unroll
        for (int kk = 0; kk < 2; ++kk) {
            const float* p = proj + (mt * 16 + l15) * D_ + kk * 32 + g * 8;
            float4 a = *(const float4*)p, c = *(const float4*)(p + 4);
            union { bf16x8 v; unsigned int u[4]; } F;
            F.u[0] = pkbf(a.x, a.y); F.u[1] = pkbf(a.z, a.w);
            F.u[2] = pkbf(c.x, c.y); F.u[3] = pkbf(c.z, c.w);
            pf[mt][kk] = F.v;
        }
    __syncthreads();

    bf16x8 af3[5][2];
#pragma unroll
    for (int ci = 0; ci < 5; ++ci)
#pragma unroll
        for (int kk = 0; kk < 2; ++kk) {
            int c = ci * 16 + l15;
            af3[ci][kk] = *(const bf16x8*)(b1tb + SWZ(c * 128 + 16 * g + 64 * kk, c));
        }

    auto loadQ = [&](int t, float4* qp) {
        int sb = s0 + t * TILE;
        const float* qrow = qb + (size_t)(sb + wid * 16 + l15) * rs;
        qp[0] = *(const float4*)(qrow + g * 8);
        qp[1] = *(const float4*)(qrow + g * 8 + 4);
        qp[2] = *(const float4*)(qrow + 32 + g * 8);
        qp[3] = *(const float4*)(qrow + 32 + g * 8 + 4);
    };

    auto body = [&](int t, int p, const float4* qc, float4* qn) {
        if (t + 1 < QTILES) loadQ(t + 1, qn);

        float kx[16];
#pragma unroll
        for (int i = 0; i < 4; ++i) {
            kx[4 * i + 0] = qc[i].x * XS_; kx[4 * i + 1] = qc[i].y * XS_;
            kx[4 * i + 2] = qc[i].z * XS_; kx[4 * i + 3] = qc[i].w * XS_;
        }
        float sq = 0.f;
#pragma unroll
        for (int j = 0; j < 16; ++j) sq += kx[j] * kx[j];
        sq += __shfl_xor(sq, 16);
        sq += __shfl_xor(sq, 32);
        float hrow = sq * HS_ + 3.0f;

        union { bf16x8 v; unsigned int u[4]; } A0, A1;
#pragma unroll
        for (int i = 0; i < 4; ++i) {
            A0.u[i] = pkbf(kx[2 * i], kx[2 * i + 1]);
            A1.u[i] = pkbf(kx[8 + 2 * i], kx[9 + 2 * i]);
        }

        f32x4 pa[4];
#pragma unroll
        for (int mt = 0; mt < 4; ++mt) {
            pa[mt] = (f32x4){0.f, 0.f, 0.f, 0.f};
            pa[mt] = MFMA(A0.v, pf[mt][0], pa[mt]);
            pa[mt] = MFMA(A1.v, pf[mt][1], pa[mt]);
        }

        float hr[4];
#pragma unroll
        for (int r = 0; r < 4; ++r) hr[r] = __shfl(hrow, 4 * g + r);

        char* elp = eLb[p];
#pragma unroll
        for (int mt = 0; mt < 4; ++mt) {
            int m = mt * 16 + l15;
            float e0 = fexp2(pa[mt][0] - hr[0]);
            float e1 = fexp2(pa[mt][1] - hr[1]);
            float e2 = fexp2(pa[mt][2] - hr[2]);
            float e3 = fexp2(pa[mt][3] - hr[3]);
            unsigned int p01 = pkbf(e0, e1), p23 = pkbf(e2, e3);
            int q0 = wid * 16 + 4 * g;
            *(unsigned short*)(elp + SWZ((q0 + 0) * 128 + 2 * m, q0 + 0)) =
                (unsigned short)p01;
            *(unsigned short*)(elp + SWZ((q0 + 1) * 128 + 2 * m, q0 + 1)) =
                (unsigned short)(p01 >> 16);
            *(unsigned short*)(elp + SWZ((q0 + 2) * 128 + 2 * m, q0 + 2)) =
                (unsigned short)p23;
            *(unsigned short*)(elp + SWZ((q0 + 3) * 128 + 2 * m, q0 + 3)) =
                (unsigned short)(p23 >> 16);
        }
        __syncthreads();

        bf16x8 b3[2];
        {
            int qrow = wid * 16 + l15;
            b3[0] = *(const bf16x8*)(elp + SWZ(qrow * 128 + 16 * g, qrow));
            b3[1] = *(const bf16x8*)(elp + SWZ(qrow * 128 + 16 * g + 64, qrow));
        }
        f32x4 dt[5];
#pragma unroll
        for (int ci = 0; ci < 5; ++ci) {
            dt[ci] = (f32x4){0.f, 0.f, 0.f, 0.f};
            dt[ci] = MFMA(af3[ci][0], b3[0], dt[ci]);
            dt[ci] = MFMA(af3[ci][1], b3[1], dt[ci]);
        }

        float den = __shfl(dt[4][0], l15);
        float rd = 1.0f / fmaxf(den, EPS_);

        int sg = s0 + t * TILE + wid * 16 + l15;
        size_t base = (((size_t)b * S_ + sg) * H_ + h) * D_;
#pragma unroll
        for (int ci = 0; ci < 4; ++ci) {
            f32x4 o;
#pragma unroll
            for (int r = 0; r < 4; ++r) o[r] = dt[ci][r] * rd;
            *(f32x4*)(out + base + ci * 16 + 4 * g) = o;
        }
    };

    float4 qa[4], qb2[4];
    loadQ(0, qa);
    for (int t = 0; t < QTILES; t += 2) {
        body(t, 0, qa, qb2);
        body(t + 1, 1, qb2, qa);
    }
}

extern "C" void kernel_launch(void* const* d_in, const int* in_sizes, int n_in,
                              void* d_out, int out_size, void* d_ws, size_t ws_size,
                              hipStream_t stream)
{
    const float* qs   = (const float*)d_in[0];
    const float* ks   = (const float*)d_in[1];
    const float* vs   = (const float*)d_in[2];
    const float* proj = (const float*)d_in[3];
    float* out = (float*)d_out;

    float* partial = (float*)d_ws;                // BH*NCHK*M*CPK (~21MB)
    float* buf1 = partial + (size_t)BH_ * NCHK * (M_ * CPK_);

    fa_k<<<dim3(NCHK, BH_), 128, 0, stream>>>(ks, vs, proj, partial);
    int nred = (BH_ * M_ * CPK_ + 255) / 256;
    fa_r<<<dim3(nred), 256, 0, stream>>>(partial, buf1, NCHK);
    fa_q<<<dim3(NCHQ, BH_), 256, 0, stream>>>(qs, proj, buf1, out);
}